// Round 17
// baseline (728.416 us; speedup 1.0000x reference)
//
#include <hip/hip_runtime.h>
#include <hip/hip_cooperative_groups.h>
#include <stdint.h>

namespace cg = cooperative_groups;

#define NN 100000
#define EE 1600000
#define DD 64
#define NBUCK 782        // ceil(NN/128): bucket b covers nodes [b*128, b*128+127]
#define SCWG 800         // blocks; hist/scatter chunks of 2000 edges
#define SCCHUNK 2000

using short8 = __attribute__((ext_vector_type(8))) short;
using f32x4  = __attribute__((ext_vector_type(4))) float;
using f2     = __attribute__((ext_vector_type(2))) float;

// ---------------- bf16 helpers ----------------

__device__ __forceinline__ unsigned short bf16_rne(float f) {
    unsigned int u = __float_as_uint(f);
    unsigned int r = (u + 0x7FFFu + ((u >> 16) & 1u)) >> 16;
    return (unsigned short)r;
}
__device__ __forceinline__ float bf16_to_f32(unsigned short h) {
    return __uint_as_float(((unsigned int)h) << 16);
}

// ---------------- fused CSR build + conversions: ONE cooperative kernel ----------------
// P0: zero bhist, convert weights (transpose+split) and x (bf16).
// P1: bucket histogram (LDS atomics). P2: bucket scan (block 0). P3: scatter. P4: per-bucket CSR.
// phase = -1: all phases with grid.sync between; phase = k: only phase k (fallback path).

__global__ __launch_bounds__(256) void csr_conv_all(
    const int* __restrict__ src, const int* __restrict__ dst,
    const float* __restrict__ Wl, const float* __restrict__ Wr, const float* __restrict__ Ws,
    const float* __restrict__ x,
    unsigned short* __restrict__ Wt_hi, unsigned short* __restrict__ Wt_lo,
    unsigned short* __restrict__ Ahi,
    int* __restrict__ bhist, int* __restrict__ bbase, int* __restrict__ bcur,
    unsigned int* __restrict__ bedges, int* __restrict__ offsets, int* __restrict__ csr,
    int phase) {
    cg::grid_group grid = cg::this_grid();
    __shared__ int sh[2 * NBUCK];
    int t = threadIdx.x;
    int b = blockIdx.x;

    // ---- P0: init + conversions ----
    if (phase < 0 || phase == 0) {
        int g = b * 256 + t;
        if (g < NBUCK) bhist[g] = 0;
        if (g < 9 * 4096) {
            int mat = g >> 12, r = g & 4095;
            int k = r >> 6, n = r & 63;
            int L = mat / 3, j = mat % 3;
            const float* W = (j == 0) ? Wl : ((j == 1) ? Wr : Ws);
            float v = W[L * 4096 + k * 64 + n];
            unsigned short hi = bf16_rne(v);
            unsigned short lo = bf16_rne(v - bf16_to_f32(hi));
            Wt_hi[mat * 4096 + n * 64 + k] = hi;
            Wt_lo[mat * 4096 + n * 64 + k] = lo;
        }
        for (int i = g; i < NN * 16; i += SCWG * 256) {
            float4 v = *(const float4*)&x[(size_t)i * 4];
            ushort4 h;
            h.x = bf16_rne(v.x); h.y = bf16_rne(v.y);
            h.z = bf16_rne(v.z); h.w = bf16_rne(v.w);
            *(ushort4*)&Ahi[(size_t)i * 4] = h;
        }
    }
    if (phase < 0) grid.sync();

    // ---- P1: histogram ----
    if (phase < 0 || phase == 1) {
        for (int i = t; i < NBUCK; i += 256) sh[i] = 0;
        __syncthreads();
        int start = b * SCCHUNK;
        int endi = min(start + SCCHUNK, EE);
        for (int e = start + t; e < endi; e += 256)
            atomicAdd(&sh[dst[e] >> 7], 1);
        __syncthreads();
        for (int i = t; i < NBUCK; i += 256)
            if (sh[i]) atomicAdd(&bhist[i], sh[i]);
    }
    if (phase < 0) grid.sync();

    // ---- P2: exclusive scan of bucket counts (block 0; 256 threads x 4 entries) ----
    if ((phase < 0 || phase == 2) && b == 0) {
        int i0 = t * 4;
        int v0 = (i0 + 0 < NBUCK) ? bhist[i0 + 0] : 0;
        int v1 = (i0 + 1 < NBUCK) ? bhist[i0 + 1] : 0;
        int v2 = (i0 + 2 < NBUCK) ? bhist[i0 + 2] : 0;
        int v3 = (i0 + 3 < NBUCK) ? bhist[i0 + 3] : 0;
        int tsum = v0 + v1 + v2 + v3;
        sh[t] = tsum;
        __syncthreads();
        for (int off = 1; off < 256; off <<= 1) {
            int a = (t >= off) ? sh[t - off] : 0;
            __syncthreads();
            sh[t] += a;
            __syncthreads();
        }
        int run = sh[t] - tsum;
        if (i0 + 0 < NBUCK) { bbase[i0 + 0] = run; bcur[i0 + 0] = run; run += v0; }
        if (i0 + 1 < NBUCK) { bbase[i0 + 1] = run; bcur[i0 + 1] = run; run += v1; }
        if (i0 + 2 < NBUCK) { bbase[i0 + 2] = run; bcur[i0 + 2] = run; run += v2; }
        if (i0 + 3 < NBUCK) { bbase[i0 + 3] = run; bcur[i0 + 3] = run; run += v3; }
        if (t == 0) { bbase[NBUCK] = EE; offsets[NN] = EE; }
    }
    if (phase < 0) grid.sync();

    // ---- P3: scatter into bucket-grouped edge array ----
    if (phase < 0 || phase == 3) {
        int* cnt  = sh;
        int* lcur = sh + NBUCK;
        for (int i = t; i < NBUCK; i += 256) cnt[i] = 0;
        __syncthreads();
        int start = b * SCCHUNK;
        int endi = min(start + SCCHUNK, EE);
        for (int e = start + t; e < endi; e += 256)
            atomicAdd(&cnt[dst[e] >> 7], 1);
        __syncthreads();
        for (int i = t; i < NBUCK; i += 256) {
            int c = cnt[i];
            lcur[i] = c ? atomicAdd(&bcur[i], c) : 0;   // reserve contiguous run
        }
        __syncthreads();
        for (int e = start + t; e < endi; e += 256) {
            int d = dst[e];
            int pos = atomicAdd(&lcur[d >> 7], 1);
            bedges[pos] = ((unsigned int)(d & 127) << 24) | (unsigned int)src[e];
        }
    }
    if (phase < 0) grid.sync();

    // ---- P4: per-bucket node-level counting sort -> offsets + csr ----
    if ((phase < 0 || phase == 4) && b < NBUCK) {
        int* ncnt = sh;
        int* lofs = sh + 128;
        int beg = bbase[b], endb = bbase[b + 1];
        if (t < 128) ncnt[t] = 0;
        __syncthreads();
        for (int e = beg + t; e < endb; e += 256)
            atomicAdd(&ncnt[bedges[e] >> 24], 1);
        __syncthreads();
        if (t < 128) lofs[t] = ncnt[t];
        __syncthreads();
        for (int off = 1; off < 128; off <<= 1) {
            int a = 0;
            if (t < 128 && t >= off) a = lofs[t - off];
            __syncthreads();
            if (t < 128) lofs[t] += a;
            __syncthreads();
        }
        int excl = 0;
        if (t < 128) {
            excl = lofs[t] - ncnt[t];
            int node = b * 128 + t;
            if (node < NN) offsets[node] = beg + excl;
        }
        __syncthreads();
        if (t < 128) ncnt[t] = beg + excl;     // reuse as cursor
        __syncthreads();
        for (int e = beg + t; e < endb; e += 256) {
            unsigned int ed = bedges[e];
            int pos = atomicAdd(&ncnt[ed >> 24], 1);
            csr[pos] = (int)(ed & 0xFFFFFFu);
        }
    }
}

// ---------------- MFMA GEMM: A bf16 x split-bf16 W, 32 rows/wave (unchanged from R16) ----------------

__global__ __launch_bounds__(256) void gemm_mfma(
    const unsigned short* __restrict__ Ahi,
    const unsigned short* __restrict__ Wt_hi, const unsigned short* __restrict__ Wt_lo,
    const float* __restrict__ bl, const float* __restrict__ br, const float* __restrict__ bs,
    unsigned short* __restrict__ Xlb, unsigned short* __restrict__ XRS) {
    int lane = threadIdx.x & 63;
    int wid  = threadIdx.x >> 6;
    int m0 = (blockIdx.x * 4 + wid) * 32;
    if (m0 >= NN) return;

    int l4 = lane & 15;
    int hi = lane >> 4;
    int koff = hi * 8;

    int arow0 = m0 + l4, arow1 = m0 + 16 + l4;
    bool ok0 = arow0 < NN, ok1 = arow1 < NN;
    int ar0 = ok0 ? arow0 : NN - 1;
    int ar1 = ok1 ? arow1 : NN - 1;

    const unsigned short* ab0 = Ahi + (size_t)ar0 * 64;
    const unsigned short* ab1 = Ahi + (size_t)ar1 * 64;
    short8 a0k0 = *(const short8*)(ab0 + koff);
    short8 a0k1 = *(const short8*)(ab0 + 32 + koff);
    short8 a1k0 = *(const short8*)(ab1 + koff);
    short8 a1k1 = *(const short8*)(ab1 + 32 + koff);

    int nbase0 = hi * 4;

#pragma unroll
    for (int m = 0; m < 3; m++) {
        const unsigned short* wh = Wt_hi + m * 4096;
        const unsigned short* wl = Wt_lo + m * 4096;
        const float* bias = (m == 0) ? bl : ((m == 1) ? br : bs);
#pragma unroll
        for (int tt = 0; tt < 4; tt++) {
            int ncol = tt * 16 + l4;                  // weight load row
            const unsigned short* bh = wh + ncol * 64 + koff;
            const unsigned short* blo = wl + ncol * 64 + koff;
            short8 bhi0 = *(const short8*)bh;
            short8 bhi1 = *(const short8*)(bh + 32);
            short8 blo0 = *(const short8*)blo;
            short8 blo1 = *(const short8*)(blo + 32);

            f32x4 acc0 = {0.f, 0.f, 0.f, 0.f};
            f32x4 acc1 = {0.f, 0.f, 0.f, 0.f};
            // swapped operands (weights as A-op) -> transposed D: lane holds 4 consecutive cols
            acc0 = __builtin_amdgcn_mfma_f32_16x16x32_bf16(bhi0, a0k0, acc0, 0, 0, 0);
            acc1 = __builtin_amdgcn_mfma_f32_16x16x32_bf16(bhi0, a1k0, acc1, 0, 0, 0);
            acc0 = __builtin_amdgcn_mfma_f32_16x16x32_bf16(bhi1, a0k1, acc0, 0, 0, 0);
            acc1 = __builtin_amdgcn_mfma_f32_16x16x32_bf16(bhi1, a1k1, acc1, 0, 0, 0);
            acc0 = __builtin_amdgcn_mfma_f32_16x16x32_bf16(blo0, a0k0, acc0, 0, 0, 0);
            acc1 = __builtin_amdgcn_mfma_f32_16x16x32_bf16(blo0, a1k0, acc1, 0, 0, 0);
            acc0 = __builtin_amdgcn_mfma_f32_16x16x32_bf16(blo1, a0k1, acc0, 0, 0, 0);
            acc1 = __builtin_amdgcn_mfma_f32_16x16x32_bf16(blo1, a1k1, acc1, 0, 0, 0);

            int nb = tt * 16 + nbase0;                // first of 4 consecutive output cols
            float4 bb = *(const float4*)&bias[nb];
            ushort4 h0, h1;
            h0.x = bf16_rne(acc0[0] + bb.x); h0.y = bf16_rne(acc0[1] + bb.y);
            h0.z = bf16_rne(acc0[2] + bb.z); h0.w = bf16_rne(acc0[3] + bb.w);
            h1.x = bf16_rne(acc1[0] + bb.x); h1.y = bf16_rne(acc1[1] + bb.y);
            h1.z = bf16_rne(acc1[2] + bb.z); h1.w = bf16_rne(acc1[3] + bb.w);
            if (m == 0) {
                if (ok0) *(ushort4*)&Xlb[(size_t)ar0 * 64 + nb] = h0;
                if (ok1) *(ushort4*)&Xlb[(size_t)ar1 * 64 + nb] = h1;
            } else {
                int coff = (m == 1) ? 0 : 64;
                if (ok0) *(ushort4*)&XRS[(size_t)ar0 * 128 + coff + nb] = h0;
                if (ok1) *(ushort4*)&XRS[(size_t)ar1 * 128 + coff + nb] = h1;
            }
        }
    }
}

// ---------------- per-node attention aggregation (R12 structure, unchanged) ----------------

__device__ __forceinline__ float group_sum16(float t) {
    t += __int_as_float(__builtin_amdgcn_update_dpp(0, __float_as_int(t), 0xB1, 0xF, 0xF, true));   // xor1
    t += __int_as_float(__builtin_amdgcn_update_dpp(0, __float_as_int(t), 0x4E, 0xF, 0xF, true));   // xor2
    t += __int_as_float(__builtin_amdgcn_update_dpp(0, __float_as_int(t), 0x141, 0xF, 0xF, true));  // row_half_mirror ~ xor4
    t += __int_as_float(__builtin_amdgcn_update_dpp(0, __float_as_int(t), 0x140, 0xF, 0xF, true));  // row_mirror ~ xor8
    return t;
}

__device__ __forceinline__ void unpack4(uint2 u, f2& v01, f2& v23) {
    v01 = f2{ __uint_as_float(u.x << 16), __uint_as_float(u.x & 0xFFFF0000u) };
    v23 = f2{ __uint_as_float(u.y << 16), __uint_as_float(u.y & 0xFFFF0000u) };
}

__global__ __launch_bounds__(256) void node_kernel(
    const unsigned short* __restrict__ Xlb, const unsigned short* __restrict__ XRS,
    const int* __restrict__ offsets, const int* __restrict__ csr,
    const float* __restrict__ att, const float* __restrict__ bg,
    unsigned short* __restrict__ hout, int do_relu,
    const float* __restrict__ Wout, const float* __restrict__ bout,
    float* __restrict__ outp, int do_out) {
    int lane = threadIdx.x & 63;
    int wid  = threadIdx.x >> 6;
    int i = blockIdx.x * 4 + wid;
    if (i >= NN) return;
    int sub = lane & 15;
    int grp = lane >> 4;

    f2 xr01, xr23;
    unpack4(*(const uint2*)&XRS[(size_t)i * 128 + sub * 4], xr01, xr23);
    float4 att4 = *(const float4*)&att[sub * 4];
    f2 at01 = {att4.x, att4.y}, at23 = {att4.z, att4.w};

    f2 agg01 = {0.f, 0.f}, agg23 = {0.f, 0.f};
    float denom = 0.f;
    int beg = offsets[i], end = offsets[i + 1];

    for (int j0 = beg; j0 < end; j0 += 8) {
        int jA = j0 + grp, jB = jA + 4;
        bool vA = jA < end, vB = jB < end;
        int sA = csr[vA ? jA : beg];
        int sB = csr[vB ? jB : beg];
        uint2 uA = *(const uint2*)&Xlb[(size_t)sA * 64 + sub * 4];
        uint2 uB = *(const uint2*)&Xlb[(size_t)sB * 64 + sub * 4];
        f2 xA01, xA23, xB01, xB23;
        unpack4(uA, xA01, xA23);
        unpack4(uB, xB01, xB23);

        f2 sA01 = xA01 + xr01;                 // v_pk_add_f32
        f2 sA23 = xA23 + xr23;
        f2 sB01 = xB01 + xr01;
        f2 sB23 = xB23 + xr23;
        f2 lA01 = { fmaxf(sA01.x, 0.2f * sA01.x), fmaxf(sA01.y, 0.2f * sA01.y) };
        f2 lA23 = { fmaxf(sA23.x, 0.2f * sA23.x), fmaxf(sA23.y, 0.2f * sA23.y) };
        f2 lB01 = { fmaxf(sB01.x, 0.2f * sB01.x), fmaxf(sB01.y, 0.2f * sB01.y) };
        f2 lB23 = { fmaxf(sB23.x, 0.2f * sB23.x), fmaxf(sB23.y, 0.2f * sB23.y) };

        f2 tAv = lA01 * at01 + lA23 * at23;    // pk_mul + pk_fma
        f2 tBv = lB01 * at01 + lB23 * at23;
        float tA = group_sum16(tAv.x + tAv.y);
        float tB = group_sum16(tBv.x + tBv.y);
        float aA = vA ? __expf(tA) : 0.f;
        float aB = vB ? __expf(tB) : 0.f;

        f2 aAv = {aA, aA};
        f2 aBv = {aB, aB};
        agg01 += aAv * xA01 + aBv * xB01;      // pk_fma chain
        agg23 += aAv * xA23 + aBv * xB23;
        denom += aA + aB;
    }

    float aggx = agg01.x, aggy = agg01.y, aggz = agg23.x, aggw = agg23.y;
#pragma unroll
    for (int m = 16; m <= 32; m <<= 1) {
        aggx  += __shfl_xor(aggx, m, 64);
        aggy  += __shfl_xor(aggy, m, 64);
        aggz  += __shfl_xor(aggz, m, 64);
        aggw  += __shfl_xor(aggw, m, 64);
        denom += __shfl_xor(denom, m, 64);
    }

    float inv = (denom > 0.f) ? (1.0f / denom) : 0.f;
    f2 sk01, sk23;
    unpack4(*(const uint2*)&XRS[(size_t)i * 128 + 64 + sub * 4], sk01, sk23);
    float4 bg4 = *(const float4*)&bg[sub * 4];
    float4 res;
    res.x = aggx * inv + bg4.x + sk01.x;
    res.y = aggy * inv + bg4.y + sk01.y;
    res.z = aggz * inv + bg4.z + sk23.x;
    res.w = aggw * inv + bg4.w + sk23.y;
    if (do_relu) {
        res.x = fmaxf(res.x, 0.f); res.y = fmaxf(res.y, 0.f);
        res.z = fmaxf(res.z, 0.f); res.w = fmaxf(res.w, 0.f);
    }
    if (do_out) {
        float4 w01 = *(const float4*)&Wout[8 * sub];
        float4 w23 = *(const float4*)&Wout[8 * sub + 4];
        float o0 = res.x * w01.x + res.y * w01.z + res.z * w23.x + res.w * w23.z;
        float o1 = res.x * w01.y + res.y * w01.w + res.z * w23.y + res.w * w23.w;
        o0 = group_sum16(o0);
        o1 = group_sum16(o1);
        if (lane == 0) {
            outp[(size_t)i * 2 + 0] = o0 + bout[0];
            outp[(size_t)i * 2 + 1] = o1 + bout[1];
        }
    } else {
        if (grp == 0) {
            ushort4 h;
            h.x = bf16_rne(res.x);
            h.y = bf16_rne(res.y);
            h.z = bf16_rne(res.z);
            h.w = bf16_rne(res.w);
            *(ushort4*)&hout[(size_t)i * 64 + sub * 4] = h;
        }
    }
}

// ---------------- launch ----------------

extern "C" void kernel_launch(void* const* d_in, const int* in_sizes, int n_in,
                              void* d_out, int out_size, void* d_ws, size_t ws_size,
                              hipStream_t stream) {
    const float* x    = (const float*)d_in[0];
    const int*   ei   = (const int*)d_in[1];
    const float* Wl   = (const float*)d_in[2];
    const float* bl   = (const float*)d_in[3];
    const float* Wr   = (const float*)d_in[4];
    const float* br   = (const float*)d_in[5];
    const float* att  = (const float*)d_in[6];
    const float* bg   = (const float*)d_in[7];
    const float* Ws   = (const float*)d_in[8];
    const float* bs   = (const float*)d_in[9];
    const float* Wout = (const float*)d_in[10];
    const float* bout = (const float*)d_in[11];
    float* out = (float*)d_out;

    size_t off = 0;
    char* base = (char*)d_ws;
    auto alloc = [&](size_t bytes) -> void* {
        void* p = base + off;
        off += (bytes + 255) & ~(size_t)255;
        return p;
    };
    unsigned short* Xlb = (unsigned short*)alloc((size_t)NN * 64 * 2);
    unsigned short* XRS = (unsigned short*)alloc((size_t)NN * 128 * 2);
    unsigned short* Ahi = (unsigned short*)alloc((size_t)NN * 64 * 2);
    unsigned short* Bhi = (unsigned short*)alloc((size_t)NN * 64 * 2);
    unsigned short* Wthi = (unsigned short*)alloc((size_t)9 * 4096 * 2);
    unsigned short* Wtlo = (unsigned short*)alloc((size_t)9 * 4096 * 2);
    int*  bhist  = (int*)alloc((size_t)NBUCK * 4);
    int*  bbase  = (int*)alloc((size_t)(NBUCK + 1) * 4);
    int*  bcur   = (int*)alloc((size_t)NBUCK * 4);
    unsigned int* bedges = (unsigned int*)alloc((size_t)EE * 4);
    int*  offs   = (int*)alloc((size_t)(NN + 1) * 4);
    int*  csr    = (int*)alloc((size_t)EE * 4);

    const int* srcp = ei;
    const int* dstp = ei + EE;

    // single cooperative dispatch for CSR build + conversions (5-6 dispatches -> 1)
    int phaseAll = -1;
    void* params[] = {
        (void*)&srcp, (void*)&dstp, (void*)&Wl, (void*)&Wr, (void*)&Ws, (void*)&x,
        (void*)&Wthi, (void*)&Wtlo, (void*)&Ahi,
        (void*)&bhist, (void*)&bbase, (void*)&bcur,
        (void*)&bedges, (void*)&offs, (void*)&csr, (void*)&phaseAll
    };
    hipError_t cerr = hipLaunchCooperativeKernel((const void*)csr_conv_all,
                                                 dim3(SCWG), dim3(256), params, 0, stream);
    if (cerr != hipSuccess) {
        (void)hipGetLastError();   // clear error; fall back to phased launches
        for (int p = 0; p < 5; p++) {
            csr_conv_all<<<SCWG, 256, 0, stream>>>(
                srcp, dstp, Wl, Wr, Ws, x, Wthi, Wtlo, Ahi,
                bhist, bbase, bcur, bedges, offs, csr, p);
        }
    }

    unsigned short* cur = Ahi;
    unsigned short* nxt = Bhi;
    for (int L = 0; L < 3; L++) {
        gemm_mfma<<<(NN + 127) / 128, 256, 0, stream>>>(
            cur, Wthi + (size_t)L * 3 * 4096, Wtlo + (size_t)L * 3 * 4096,
            bl + L * 64, br + L * 64, bs + L * 64, Xlb, XRS);
        node_kernel<<<NN / 4, 256, 0, stream>>>(
            Xlb, XRS, offs, csr, att + L * 64, bg + L * 64,
            nxt, (L < 2) ? 1 : 0,
            Wout, bout, out, (L == 2) ? 1 : 0);
        unsigned short* tp = cur; cur = nxt; nxt = tp;
    }
}

// Round 18
// 340.435 us; speedup vs baseline: 2.1397x; 2.1397x over previous
//
#include <hip/hip_runtime.h>
#include <stdint.h>

#define NN 100000
#define EE 1600000
#define DD 64
#define NBUCK 391        // ceil(NN/256): bucket b covers nodes [b*256, b*256+255]
#define SCWG 200         // hist/scatter workgroups; 8000 edges each
#define SCCHUNK 8000

using short8 = __attribute__((ext_vector_type(8))) short;
using f32x4  = __attribute__((ext_vector_type(4))) float;
using f2     = __attribute__((ext_vector_type(2))) float;

// ---------------- bf16 helpers ----------------

__device__ __forceinline__ unsigned short bf16_rne(float f) {
    unsigned int u = __float_as_uint(f);
    unsigned int r = (u + 0x7FFFu + ((u >> 16) & 1u)) >> 16;
    return (unsigned short)r;
}
__device__ __forceinline__ float bf16_to_f32(unsigned short h) {
    return __uint_as_float(((unsigned int)h) << 16);
}

// ---------------- CSR build via bucketed counting sort ----------------
// bedges packs (dst&255)<<24 | src  (src < 2^24): 4B per edge.
// 8000 edges/chunk over 391 buckets -> ~20 edges/bucket-run (80B) -> low write amplification.

__global__ void bucket_hist(const int* __restrict__ dst, int* __restrict__ bhist) {
    __shared__ int h[NBUCK];
    int t = threadIdx.x;
    for (int b = t; b < NBUCK; b += 256) h[b] = 0;
    __syncthreads();
    int start = blockIdx.x * SCCHUNK;
    int endi = min(start + SCCHUNK, EE);
    for (int e = start + t; e < endi; e += 256)
        atomicAdd(&h[dst[e] >> 8], 1);
    __syncthreads();
    for (int b = t; b < NBUCK; b += 256)
        if (h[b]) atomicAdd(&bhist[b], h[b]);
}

__global__ void bucket_scan(const int* __restrict__ bhist, int* __restrict__ bbase,
                            int* __restrict__ bcursor, int* __restrict__ offsets) {
    __shared__ int s[512];
    int t = threadIdx.x;
    int v = (t < NBUCK) ? bhist[t] : 0;
    s[t] = v;
    __syncthreads();
    for (int off = 1; off < 512; off <<= 1) {
        int a = (t >= off) ? s[t - off] : 0;
        __syncthreads();
        s[t] += a;
        __syncthreads();
    }
    if (t < NBUCK) { int excl = s[t] - v; bbase[t] = excl; bcursor[t] = excl; }
    if (t == 0) { bbase[NBUCK] = EE; offsets[NN] = EE; }
}

__global__ void bucket_scatter(const int* __restrict__ src, const int* __restrict__ dst,
                               int* __restrict__ bcursor, unsigned int* __restrict__ bedges) {
    __shared__ int cnt[NBUCK];
    __shared__ int lcur[NBUCK];
    int t = threadIdx.x;
    for (int b = t; b < NBUCK; b += 256) cnt[b] = 0;
    __syncthreads();
    int start = blockIdx.x * SCCHUNK;
    int endi = min(start + SCCHUNK, EE);
    for (int e = start + t; e < endi; e += 256)
        atomicAdd(&cnt[dst[e] >> 8], 1);
    __syncthreads();
    for (int b = t; b < NBUCK; b += 256) {
        int c = cnt[b];
        lcur[b] = c ? atomicAdd(&bcursor[b], c) : 0;   // reserve contiguous run
    }
    __syncthreads();
    for (int e = start + t; e < endi; e += 256) {
        int d = dst[e];
        int pos = atomicAdd(&lcur[d >> 8], 1);
        bedges[pos] = ((unsigned int)(d & 255) << 24) | (unsigned int)src[e];
    }
}

__global__ void bucket_csr(const unsigned int* __restrict__ bedges, const int* __restrict__ bbase,
                           int* __restrict__ offsets, int* __restrict__ csr) {
    __shared__ int ncnt[256];
    __shared__ int lofs[256];
    int b = blockIdx.x;
    int t = threadIdx.x;
    int beg = bbase[b], endb = bbase[b + 1];
    ncnt[t] = 0;
    __syncthreads();
    for (int e = beg + t; e < endb; e += 256)
        atomicAdd(&ncnt[bedges[e] >> 24], 1);
    __syncthreads();
    int v = ncnt[t];
    lofs[t] = v;
    __syncthreads();
    for (int off = 1; off < 256; off <<= 1) {
        int a = (t >= off) ? lofs[t - off] : 0;
        __syncthreads();
        lofs[t] += a;
        __syncthreads();
    }
    int excl = lofs[t] - v;
    int node = b * 256 + t;
    if (node < NN) offsets[node] = beg + excl;
    __syncthreads();
    ncnt[t] = beg + excl;                  // reuse as cursor
    __syncthreads();
    for (int e = beg + t; e < endb; e += 256) {
        unsigned int ed = bedges[e];
        int pos = atomicAdd(&ncnt[ed >> 24], 1);
        csr[pos] = (int)(ed & 0xFFFFFFu);
    }
}

// ---------------- fused conversion: weights (transposed, split hi/lo) + x (bf16 hi only) ----------------

__global__ void conv_wx(const float* __restrict__ Wl, const float* __restrict__ Wr,
                        const float* __restrict__ Ws, const float* __restrict__ x,
                        unsigned short* __restrict__ Wt_hi, unsigned short* __restrict__ Wt_lo,
                        unsigned short* __restrict__ Ahi) {
    if (blockIdx.x < 144) {
        int e = blockIdx.x * 256 + threadIdx.x;
        if (e >= 9 * 4096) return;
        int mat = e >> 12;          // 0..8 = L*3 + j
        int r   = e & 4095;
        int k   = r >> 6, n = r & 63;
        int L = mat / 3, j = mat % 3;
        const float* W = (j == 0) ? Wl : ((j == 1) ? Wr : Ws);
        float v = W[L * 4096 + k * 64 + n];
        unsigned short hi = bf16_rne(v);
        unsigned short lo = bf16_rne(v - bf16_to_f32(hi));
        Wt_hi[mat * 4096 + n * 64 + k] = hi;
        Wt_lo[mat * 4096 + n * 64 + k] = lo;
    } else {
        int i = (blockIdx.x - 144) * 256 + threadIdx.x;     // one float4 per thread
        int total = NN * 16;
        int stride = (gridDim.x - 144) * 256;
        for (; i < total; i += stride) {
            float4 v = *(const float4*)&x[(size_t)i * 4];
            ushort4 h;
            h.x = bf16_rne(v.x);
            h.y = bf16_rne(v.y);
            h.z = bf16_rne(v.z);
            h.w = bf16_rne(v.w);
            *(ushort4*)&Ahi[(size_t)i * 4] = h;
        }
    }
}

// ---------------- MFMA GEMM: A bf16 (hi only) x split-bf16 W, 32 rows/wave ----------------
// C = Ahi*(Whi+Wlo): A is already bf16-rounded (same error class as the bf16 gather buffer).
// 8 MFMAs/tile for 2 row-sets; transposed D -> contiguous ushort4 stores.

__global__ __launch_bounds__(256) void gemm_mfma(
    const unsigned short* __restrict__ Ahi,
    const unsigned short* __restrict__ Wt_hi, const unsigned short* __restrict__ Wt_lo,
    const float* __restrict__ bl, const float* __restrict__ br, const float* __restrict__ bs,
    unsigned short* __restrict__ Xlb, unsigned short* __restrict__ XRS) {
    int lane = threadIdx.x & 63;
    int wid  = threadIdx.x >> 6;
    int m0 = (blockIdx.x * 4 + wid) * 32;
    if (m0 >= NN) return;

    int l4 = lane & 15;
    int hi = lane >> 4;
    int koff = hi * 8;

    int arow0 = m0 + l4, arow1 = m0 + 16 + l4;
    bool ok0 = arow0 < NN, ok1 = arow1 < NN;
    int ar0 = ok0 ? arow0 : NN - 1;
    int ar1 = ok1 ? arow1 : NN - 1;

    const unsigned short* ab0 = Ahi + (size_t)ar0 * 64;
    const unsigned short* ab1 = Ahi + (size_t)ar1 * 64;
    short8 a0k0 = *(const short8*)(ab0 + koff);
    short8 a0k1 = *(const short8*)(ab0 + 32 + koff);
    short8 a1k0 = *(const short8*)(ab1 + koff);
    short8 a1k1 = *(const short8*)(ab1 + 32 + koff);

    int nbase0 = hi * 4;

#pragma unroll
    for (int m = 0; m < 3; m++) {
        const unsigned short* wh = Wt_hi + m * 4096;
        const unsigned short* wl = Wt_lo + m * 4096;
        const float* bias = (m == 0) ? bl : ((m == 1) ? br : bs);
#pragma unroll
        for (int tt = 0; tt < 4; tt++) {
            int ncol = tt * 16 + l4;                  // weight load row
            const unsigned short* bh = wh + ncol * 64 + koff;
            const unsigned short* blo = wl + ncol * 64 + koff;
            short8 bhi0 = *(const short8*)bh;
            short8 bhi1 = *(const short8*)(bh + 32);
            short8 blo0 = *(const short8*)blo;
            short8 blo1 = *(const short8*)(blo + 32);

            f32x4 acc0 = {0.f, 0.f, 0.f, 0.f};
            f32x4 acc1 = {0.f, 0.f, 0.f, 0.f};
            // swapped operands (weights as A-op) -> transposed D: lane holds 4 consecutive cols
            acc0 = __builtin_amdgcn_mfma_f32_16x16x32_bf16(bhi0, a0k0, acc0, 0, 0, 0);
            acc1 = __builtin_amdgcn_mfma_f32_16x16x32_bf16(bhi0, a1k0, acc1, 0, 0, 0);
            acc0 = __builtin_amdgcn_mfma_f32_16x16x32_bf16(bhi1, a0k1, acc0, 0, 0, 0);
            acc1 = __builtin_amdgcn_mfma_f32_16x16x32_bf16(bhi1, a1k1, acc1, 0, 0, 0);
            acc0 = __builtin_amdgcn_mfma_f32_16x16x32_bf16(blo0, a0k0, acc0, 0, 0, 0);
            acc1 = __builtin_amdgcn_mfma_f32_16x16x32_bf16(blo0, a1k0, acc1, 0, 0, 0);
            acc0 = __builtin_amdgcn_mfma_f32_16x16x32_bf16(blo1, a0k1, acc0, 0, 0, 0);
            acc1 = __builtin_amdgcn_mfma_f32_16x16x32_bf16(blo1, a1k1, acc1, 0, 0, 0);

            int nb = tt * 16 + nbase0;                // first of 4 consecutive output cols
            float4 bb = *(const float4*)&bias[nb];
            ushort4 h0, h1;
            h0.x = bf16_rne(acc0[0] + bb.x); h0.y = bf16_rne(acc0[1] + bb.y);
            h0.z = bf16_rne(acc0[2] + bb.z); h0.w = bf16_rne(acc0[3] + bb.w);
            h1.x = bf16_rne(acc1[0] + bb.x); h1.y = bf16_rne(acc1[1] + bb.y);
            h1.z = bf16_rne(acc1[2] + bb.z); h1.w = bf16_rne(acc1[3] + bb.w);
            if (m == 0) {
                if (ok0) *(ushort4*)&Xlb[(size_t)ar0 * 64 + nb] = h0;
                if (ok1) *(ushort4*)&Xlb[(size_t)ar1 * 64 + nb] = h1;
            } else {
                int coff = (m == 1) ? 0 : 64;
                if (ok0) *(ushort4*)&XRS[(size_t)ar0 * 128 + coff + nb] = h0;
                if (ok1) *(ushort4*)&XRS[(size_t)ar1 * 128 + coff + nb] = h1;
            }
        }
    }
}

// ---------------- per-node attention aggregation (R12 structure: 8 edges/iter, __expf) ----------------

__device__ __forceinline__ float group_sum16(float t) {
    t += __int_as_float(__builtin_amdgcn_update_dpp(0, __float_as_int(t), 0xB1, 0xF, 0xF, true));   // xor1
    t += __int_as_float(__builtin_amdgcn_update_dpp(0, __float_as_int(t), 0x4E, 0xF, 0xF, true));   // xor2
    t += __int_as_float(__builtin_amdgcn_update_dpp(0, __float_as_int(t), 0x141, 0xF, 0xF, true));  // row_half_mirror ~ xor4
    t += __int_as_float(__builtin_amdgcn_update_dpp(0, __float_as_int(t), 0x140, 0xF, 0xF, true));  // row_mirror ~ xor8
    return t;
}

__device__ __forceinline__ void unpack4(uint2 u, f2& v01, f2& v23) {
    v01 = f2{ __uint_as_float(u.x << 16), __uint_as_float(u.x & 0xFFFF0000u) };
    v23 = f2{ __uint_as_float(u.y << 16), __uint_as_float(u.y & 0xFFFF0000u) };
}

__global__ __launch_bounds__(256) void node_kernel(
    const unsigned short* __restrict__ Xlb, const unsigned short* __restrict__ XRS,
    const int* __restrict__ offsets, const int* __restrict__ csr,
    const float* __restrict__ att, const float* __restrict__ bg,
    unsigned short* __restrict__ hout, int do_relu,
    const float* __restrict__ Wout, const float* __restrict__ bout,
    float* __restrict__ outp, int do_out) {
    int lane = threadIdx.x & 63;
    int wid  = threadIdx.x >> 6;
    int i = blockIdx.x * 4 + wid;
    if (i >= NN) return;
    int sub = lane & 15;
    int grp = lane >> 4;

    f2 xr01, xr23;
    unpack4(*(const uint2*)&XRS[(size_t)i * 128 + sub * 4], xr01, xr23);
    float4 att4 = *(const float4*)&att[sub * 4];
    f2 at01 = {att4.x, att4.y}, at23 = {att4.z, att4.w};

    f2 agg01 = {0.f, 0.f}, agg23 = {0.f, 0.f};
    float denom = 0.f;
    int beg = offsets[i], end = offsets[i + 1];

    for (int j0 = beg; j0 < end; j0 += 8) {
        int jA = j0 + grp, jB = jA + 4;
        bool vA = jA < end, vB = jB < end;
        int sA = csr[vA ? jA : beg];
        int sB = csr[vB ? jB : beg];
        uint2 uA = *(const uint2*)&Xlb[(size_t)sA * 64 + sub * 4];
        uint2 uB = *(const uint2*)&Xlb[(size_t)sB * 64 + sub * 4];
        f2 xA01, xA23, xB01, xB23;
        unpack4(uA, xA01, xA23);
        unpack4(uB, xB01, xB23);

        f2 sA01 = xA01 + xr01;                 // v_pk_add_f32
        f2 sA23 = xA23 + xr23;
        f2 sB01 = xB01 + xr01;
        f2 sB23 = xB23 + xr23;
        f2 lA01 = { fmaxf(sA01.x, 0.2f * sA01.x), fmaxf(sA01.y, 0.2f * sA01.y) };
        f2 lA23 = { fmaxf(sA23.x, 0.2f * sA23.x), fmaxf(sA23.y, 0.2f * sA23.y) };
        f2 lB01 = { fmaxf(sB01.x, 0.2f * sB01.x), fmaxf(sB01.y, 0.2f * sB01.y) };
        f2 lB23 = { fmaxf(sB23.x, 0.2f * sB23.x), fmaxf(sB23.y, 0.2f * sB23.y) };

        f2 tAv = lA01 * at01 + lA23 * at23;    // pk_mul + pk_fma
        f2 tBv = lB01 * at01 + lB23 * at23;
        float tA = group_sum16(tAv.x + tAv.y);
        float tB = group_sum16(tBv.x + tBv.y);
        float aA = vA ? __expf(tA) : 0.f;
        float aB = vB ? __expf(tB) : 0.f;

        f2 aAv = {aA, aA};
        f2 aBv = {aB, aB};
        agg01 += aAv * xA01 + aBv * xB01;      // pk_fma chain
        agg23 += aAv * xA23 + aBv * xB23;
        denom += aA + aB;
    }

    float aggx = agg01.x, aggy = agg01.y, aggz = agg23.x, aggw = agg23.y;
#pragma unroll
    for (int m = 16; m <= 32; m <<= 1) {
        aggx  += __shfl_xor(aggx, m, 64);
        aggy  += __shfl_xor(aggy, m, 64);
        aggz  += __shfl_xor(aggz, m, 64);
        aggw  += __shfl_xor(aggw, m, 64);
        denom += __shfl_xor(denom, m, 64);
    }

    float inv = (denom > 0.f) ? (1.0f / denom) : 0.f;
    f2 sk01, sk23;
    unpack4(*(const uint2*)&XRS[(size_t)i * 128 + 64 + sub * 4], sk01, sk23);
    float4 bg4 = *(const float4*)&bg[sub * 4];
    float4 res;
    res.x = aggx * inv + bg4.x + sk01.x;
    res.y = aggy * inv + bg4.y + sk01.y;
    res.z = aggz * inv + bg4.z + sk23.x;
    res.w = aggw * inv + bg4.w + sk23.y;
    if (do_relu) {
        res.x = fmaxf(res.x, 0.f); res.y = fmaxf(res.y, 0.f);
        res.z = fmaxf(res.z, 0.f); res.w = fmaxf(res.w, 0.f);
    }
    if (do_out) {
        float4 w01 = *(const float4*)&Wout[8 * sub];
        float4 w23 = *(const float4*)&Wout[8 * sub + 4];
        float o0 = res.x * w01.x + res.y * w01.z + res.z * w23.x + res.w * w23.z;
        float o1 = res.x * w01.y + res.y * w01.w + res.z * w23.y + res.w * w23.w;
        o0 = group_sum16(o0);
        o1 = group_sum16(o1);
        if (lane == 0) {
            outp[(size_t)i * 2 + 0] = o0 + bout[0];
            outp[(size_t)i * 2 + 1] = o1 + bout[1];
        }
    } else {
        if (grp == 0) {
            ushort4 h;
            h.x = bf16_rne(res.x);
            h.y = bf16_rne(res.y);
            h.z = bf16_rne(res.z);
            h.w = bf16_rne(res.w);
            *(ushort4*)&hout[(size_t)i * 64 + sub * 4] = h;
        }
    }
}

// ---------------- launch ----------------

extern "C" void kernel_launch(void* const* d_in, const int* in_sizes, int n_in,
                              void* d_out, int out_size, void* d_ws, size_t ws_size,
                              hipStream_t stream) {
    const float* x    = (const float*)d_in[0];
    const int*   ei   = (const int*)d_in[1];
    const float* Wl   = (const float*)d_in[2];
    const float* bl   = (const float*)d_in[3];
    const float* Wr   = (const float*)d_in[4];
    const float* br   = (const float*)d_in[5];
    const float* att  = (const float*)d_in[6];
    const float* bg   = (const float*)d_in[7];
    const float* Ws   = (const float*)d_in[8];
    const float* bs   = (const float*)d_in[9];
    const float* Wout = (const float*)d_in[10];
    const float* bout = (const float*)d_in[11];
    float* out = (float*)d_out;

    size_t off = 0;
    char* base = (char*)d_ws;
    auto alloc = [&](size_t bytes) -> void* {
        void* p = base + off;
        off += (bytes + 255) & ~(size_t)255;
        return p;
    };
    unsigned short* Xlb = (unsigned short*)alloc((size_t)NN * 64 * 2);
    unsigned short* XRS = (unsigned short*)alloc((size_t)NN * 128 * 2);
    unsigned short* Ahi = (unsigned short*)alloc((size_t)NN * 64 * 2);
    unsigned short* Bhi = (unsigned short*)alloc((size_t)NN * 64 * 2);
    unsigned short* Wthi = (unsigned short*)alloc((size_t)9 * 4096 * 2);
    unsigned short* Wtlo = (unsigned short*)alloc((size_t)9 * 4096 * 2);
    int*  bhist  = (int*)alloc((size_t)NBUCK * 4);
    int*  bbase  = (int*)alloc((size_t)(NBUCK + 1) * 4);
    int*  bcur   = (int*)alloc((size_t)NBUCK * 4);
    unsigned int* bedges = (unsigned int*)alloc((size_t)EE * 4);
    int*  offs   = (int*)alloc((size_t)(NN + 1) * 4);
    int*  csr    = (int*)alloc((size_t)EE * 4);

    const int* src = ei;
    const int* dst = ei + EE;

    hipMemsetAsync(bhist, 0, (size_t)NBUCK * 4, stream);
    bucket_hist<<<SCWG, 256, 0, stream>>>(dst, bhist);
    bucket_scan<<<1, 512, 0, stream>>>(bhist, bbase, bcur, offs);
    bucket_scatter<<<SCWG, 256, 0, stream>>>(src, dst, bcur, bedges);
    bucket_csr<<<NBUCK, 256, 0, stream>>>(bedges, bbase, offs, csr);

    conv_wx<<<144 + 400, 256, 0, stream>>>(Wl, Wr, Ws, x, Wthi, Wtlo, Ahi);

    unsigned short* cur = Ahi;
    unsigned short* nxt = Bhi;
    for (int L = 0; L < 3; L++) {
        gemm_mfma<<<(NN + 127) / 128, 256, 0, stream>>>(
            cur, Wthi + (size_t)L * 3 * 4096, Wtlo + (size_t)L * 3 * 4096,
            bl + L * 64, br + L * 64, bs + L * 64, Xlb, XRS);
        node_kernel<<<NN / 4, 256, 0, stream>>>(
            Xlb, XRS, offs, csr, att + L * 64, bg + L * 64,
            nxt, (L < 2) ? 1 : 0,
            Wout, bout, out, (L == 2) ? 1 : 0);
        unsigned short* tp = cur; cur = nxt; nxt = tp;
    }
}

// Round 19
// 336.025 us; speedup vs baseline: 2.1677x; 1.0131x over previous
//
#include <hip/hip_runtime.h>
#include <stdint.h>

#define NN 100000
#define EE 1600000
#define DD 64
#define NBUCK 391        // ceil(NN/256): bucket b covers nodes [b*256, b*256+255]
#define SCWG 200         // hist/scatter workgroups; 8000 edges each
#define SCCHUNK 8000

using short8 = __attribute__((ext_vector_type(8))) short;
using f32x4  = __attribute__((ext_vector_type(4))) float;
using f2     = __attribute__((ext_vector_type(2))) float;

// ---------------- bf16 helpers ----------------

__device__ __forceinline__ unsigned short bf16_rne(float f) {
    unsigned int u = __float_as_uint(f);
    unsigned int r = (u + 0x7FFFu + ((u >> 16) & 1u)) >> 16;
    return (unsigned short)r;
}
__device__ __forceinline__ float bf16_to_f32(unsigned short h) {
    return __uint_as_float(((unsigned int)h) << 16);
}
__device__ __forceinline__ void unpack8(uint4 u, f2& v0, f2& v1, f2& v2, f2& v3) {
    v0 = f2{ __uint_as_float(u.x << 16), __uint_as_float(u.x & 0xFFFF0000u) };
    v1 = f2{ __uint_as_float(u.y << 16), __uint_as_float(u.y & 0xFFFF0000u) };
    v2 = f2{ __uint_as_float(u.z << 16), __uint_as_float(u.z & 0xFFFF0000u) };
    v3 = f2{ __uint_as_float(u.w << 16), __uint_as_float(u.w & 0xFFFF0000u) };
}

// ---------------- fused histogram (per-block partials, no atomics) + conversions ----------------
// blocks [0,SCWG): edge histogram -> bhistPart[b][NBUCK]
// blocks [SCWG, SCWG+144): weight transpose+split
// blocks [SCWG+144, ...): x -> bf16

__global__ void hist_conv(const int* __restrict__ dst, int* __restrict__ bhistPart,
                          const float* __restrict__ Wl, const float* __restrict__ Wr,
                          const float* __restrict__ Ws, const float* __restrict__ x,
                          unsigned short* __restrict__ Wt_hi, unsigned short* __restrict__ Wt_lo,
                          unsigned short* __restrict__ Ahi) {
    int b = blockIdx.x;
    int t = threadIdx.x;
    if (b < SCWG) {
        __shared__ int h[NBUCK];
        for (int i = t; i < NBUCK; i += 256) h[i] = 0;
        __syncthreads();
        int start = b * SCCHUNK;
        int endi = min(start + SCCHUNK, EE);
        for (int e = start + t; e < endi; e += 256)
            atomicAdd(&h[dst[e] >> 8], 1);
        __syncthreads();
        for (int i = t; i < NBUCK; i += 256)
            bhistPart[b * NBUCK + i] = h[i];               // coalesced, non-atomic
    } else if (b < SCWG + 144) {
        int e = (b - SCWG) * 256 + t;
        if (e >= 9 * 4096) return;
        int mat = e >> 12;          // 0..8 = L*3 + j
        int r   = e & 4095;
        int k   = r >> 6, n = r & 63;
        int L = mat / 3, j = mat % 3;
        const float* W = (j == 0) ? Wl : ((j == 1) ? Wr : Ws);
        float v = W[L * 4096 + k * 64 + n];
        unsigned short hi = bf16_rne(v);
        unsigned short lo = bf16_rne(v - bf16_to_f32(hi));
        Wt_hi[mat * 4096 + n * 64 + k] = hi;
        Wt_lo[mat * 4096 + n * 64 + k] = lo;
    } else {
        int i = (b - SCWG - 144) * 256 + t;                // one float4 per thread
        int total = NN * 16;
        int stride = (gridDim.x - SCWG - 144) * 256;
        for (; i < total; i += stride) {
            float4 v = *(const float4*)&x[(size_t)i * 4];
            ushort4 h;
            h.x = bf16_rne(v.x);
            h.y = bf16_rne(v.y);
            h.z = bf16_rne(v.z);
            h.w = bf16_rne(v.w);
            *(ushort4*)&Ahi[(size_t)i * 4] = h;
        }
    }
}

// scan over summed partials -> bbase/bcursor
__global__ void bucket_scan(const int* __restrict__ bhistPart, int* __restrict__ bbase,
                            int* __restrict__ bcursor, int* __restrict__ offsets) {
    __shared__ int s[512];
    int t = threadIdx.x;
    int v = 0;
    if (t < NBUCK) {
        for (int w = 0; w < SCWG; w++) v += bhistPart[w * NBUCK + t];
    }
    s[t] = v;
    __syncthreads();
    for (int off = 1; off < 512; off <<= 1) {
        int a = (t >= off) ? s[t - off] : 0;
        __syncthreads();
        s[t] += a;
        __syncthreads();
    }
    if (t < NBUCK) { int excl = s[t] - v; bbase[t] = excl; bcursor[t] = excl; }
    if (t == 0) { bbase[NBUCK] = EE; offsets[NN] = EE; }
}

// scatter reuses this block's partial histogram (one pass over edges)
__global__ void bucket_scatter(const int* __restrict__ src, const int* __restrict__ dst,
                               const int* __restrict__ bhistPart,
                               int* __restrict__ bcursor, unsigned int* __restrict__ bedges) {
    __shared__ int lcur[NBUCK];
    int t = threadIdx.x;
    int b = blockIdx.x;
    for (int i = t; i < NBUCK; i += 256) {
        int c = bhistPart[b * NBUCK + i];
        lcur[i] = c ? atomicAdd(&bcursor[i], c) : 0;       // reserve contiguous run
    }
    __syncthreads();
    int start = b * SCCHUNK;
    int endi = min(start + SCCHUNK, EE);
    for (int e = start + t; e < endi; e += 256) {
        int d = dst[e];
        int pos = atomicAdd(&lcur[d >> 8], 1);
        bedges[pos] = ((unsigned int)(d & 255) << 24) | (unsigned int)src[e];
    }
}

__global__ void bucket_csr(const unsigned int* __restrict__ bedges, const int* __restrict__ bbase,
                           int* __restrict__ offsets, int* __restrict__ csr) {
    __shared__ int ncnt[256];
    __shared__ int lofs[256];
    int b = blockIdx.x;
    int t = threadIdx.x;
    int beg = bbase[b], endb = bbase[b + 1];
    ncnt[t] = 0;
    __syncthreads();
    for (int e = beg + t; e < endb; e += 256)
        atomicAdd(&ncnt[bedges[e] >> 24], 1);
    __syncthreads();
    int v = ncnt[t];
    lofs[t] = v;
    __syncthreads();
    for (int off = 1; off < 256; off <<= 1) {
        int a = (t >= off) ? lofs[t - off] : 0;
        __syncthreads();
        lofs[t] += a;
        __syncthreads();
    }
    int excl = lofs[t] - v;
    int node = b * 256 + t;
    if (node < NN) offsets[node] = beg + excl;
    __syncthreads();
    ncnt[t] = beg + excl;                  // reuse as cursor
    __syncthreads();
    for (int e = beg + t; e < endb; e += 256) {
        unsigned int ed = bedges[e];
        int pos = atomicAdd(&ncnt[ed >> 24], 1);
        csr[pos] = (int)(ed & 0xFFFFFFu);
    }
}

// ---------------- MFMA GEMM: A bf16 x split-bf16 W, 32 rows/wave (unchanged) ----------------

__global__ __launch_bounds__(256) void gemm_mfma(
    const unsigned short* __restrict__ Ahi,
    const unsigned short* __restrict__ Wt_hi, const unsigned short* __restrict__ Wt_lo,
    const float* __restrict__ bl, const float* __restrict__ br, const float* __restrict__ bs,
    unsigned short* __restrict__ Xlb, unsigned short* __restrict__ XRS) {
    int lane = threadIdx.x & 63;
    int wid  = threadIdx.x >> 6;
    int m0 = (blockIdx.x * 4 + wid) * 32;
    if (m0 >= NN) return;

    int l4 = lane & 15;
    int hi = lane >> 4;
    int koff = hi * 8;

    int arow0 = m0 + l4, arow1 = m0 + 16 + l4;
    bool ok0 = arow0 < NN, ok1 = arow1 < NN;
    int ar0 = ok0 ? arow0 : NN - 1;
    int ar1 = ok1 ? arow1 : NN - 1;

    const unsigned short* ab0 = Ahi + (size_t)ar0 * 64;
    const unsigned short* ab1 = Ahi + (size_t)ar1 * 64;
    short8 a0k0 = *(const short8*)(ab0 + koff);
    short8 a0k1 = *(const short8*)(ab0 + 32 + koff);
    short8 a1k0 = *(const short8*)(ab1 + koff);
    short8 a1k1 = *(const short8*)(ab1 + 32 + koff);

    int nbase0 = hi * 4;

#pragma unroll
    for (int m = 0; m < 3; m++) {
        const unsigned short* wh = Wt_hi + m * 4096;
        const unsigned short* wl = Wt_lo + m * 4096;
        const float* bias = (m == 0) ? bl : ((m == 1) ? br : bs);
#pragma unroll
        for (int tt = 0; tt < 4; tt++) {
            int ncol = tt * 16 + l4;                  // weight load row
            const unsigned short* bh = wh + ncol * 64 + koff;
            const unsigned short* blo = wl + ncol * 64 + koff;
            short8 bhi0 = *(const short8*)bh;
            short8 bhi1 = *(const short8*)(bh + 32);
            short8 blo0 = *(const short8*)blo;
            short8 blo1 = *(const short8*)(blo + 32);

            f32x4 acc0 = {0.f, 0.f, 0.f, 0.f};
            f32x4 acc1 = {0.f, 0.f, 0.f, 0.f};
            acc0 = __builtin_amdgcn_mfma_f32_16x16x32_bf16(bhi0, a0k0, acc0, 0, 0, 0);
            acc1 = __builtin_amdgcn_mfma_f32_16x16x32_bf16(bhi0, a1k0, acc1, 0, 0, 0);
            acc0 = __builtin_amdgcn_mfma_f32_16x16x32_bf16(bhi1, a0k1, acc0, 0, 0, 0);
            acc1 = __builtin_amdgcn_mfma_f32_16x16x32_bf16(bhi1, a1k1, acc1, 0, 0, 0);
            acc0 = __builtin_amdgcn_mfma_f32_16x16x32_bf16(blo0, a0k0, acc0, 0, 0, 0);
            acc1 = __builtin_amdgcn_mfma_f32_16x16x32_bf16(blo0, a1k0, acc1, 0, 0, 0);
            acc0 = __builtin_amdgcn_mfma_f32_16x16x32_bf16(blo1, a0k1, acc0, 0, 0, 0);
            acc1 = __builtin_amdgcn_mfma_f32_16x16x32_bf16(blo1, a1k1, acc1, 0, 0, 0);

            int nb = tt * 16 + nbase0;                // first of 4 consecutive output cols
            float4 bb = *(const float4*)&bias[nb];
            ushort4 h0, h1;
            h0.x = bf16_rne(acc0[0] + bb.x); h0.y = bf16_rne(acc0[1] + bb.y);
            h0.z = bf16_rne(acc0[2] + bb.z); h0.w = bf16_rne(acc0[3] + bb.w);
            h1.x = bf16_rne(acc1[0] + bb.x); h1.y = bf16_rne(acc1[1] + bb.y);
            h1.z = bf16_rne(acc1[2] + bb.z); h1.w = bf16_rne(acc1[3] + bb.w);
            if (m == 0) {
                if (ok0) *(ushort4*)&Xlb[(size_t)ar0 * 64 + nb] = h0;
                if (ok1) *(ushort4*)&Xlb[(size_t)ar1 * 64 + nb] = h1;
            } else {
                int coff = (m == 1) ? 0 : 64;
                if (ok0) *(ushort4*)&XRS[(size_t)ar0 * 128 + coff + nb] = h0;
                if (ok1) *(ushort4*)&XRS[(size_t)ar1 * 128 + coff + nb] = h1;
            }
        }
    }
}

// ---------------- per-node attention aggregation: 8 lanes/edge, 8 edges/batch ----------------
// Lane owns 8 features (one uint4 gather); 3-step DPP reduce per batch; 1 exp per batch.

__device__ __forceinline__ float group_sum8(float t) {
    t += __int_as_float(__builtin_amdgcn_update_dpp(0, __float_as_int(t), 0xB1, 0xF, 0xF, true));   // xor1
    t += __int_as_float(__builtin_amdgcn_update_dpp(0, __float_as_int(t), 0x4E, 0xF, 0xF, true));   // xor2
    t += __int_as_float(__builtin_amdgcn_update_dpp(0, __float_as_int(t), 0x141, 0xF, 0xF, true));  // row_half_mirror ~ xor4
    return t;
}
__device__ __forceinline__ float cross_group(float t) {
    t += __int_as_float(__builtin_amdgcn_ds_swizzle(__float_as_int(t), 0x201F));   // xor8
    t += __int_as_float(__builtin_amdgcn_ds_swizzle(__float_as_int(t), 0x401F));   // xor16
    t += __shfl_xor(t, 32, 64);                                                    // xor32
    return t;
}

__global__ __launch_bounds__(256) void node_kernel(
    const unsigned short* __restrict__ Xlb, const unsigned short* __restrict__ XRS,
    const int* __restrict__ offsets, const int* __restrict__ csr,
    const float* __restrict__ att, const float* __restrict__ bg,
    unsigned short* __restrict__ hout, int do_relu,
    const float* __restrict__ Wout, const float* __restrict__ bout,
    float* __restrict__ outp, int do_out) {
    int lane = threadIdx.x & 63;
    int wid  = threadIdx.x >> 6;
    int i = blockIdx.x * 4 + wid;
    if (i >= NN) return;
    int sub = lane & 7;    // feature octet: features sub*8 .. sub*8+7
    int grp = lane >> 3;   // edge slot 0..7

    f2 xr0, xr1, xr2, xr3;
    unpack8(*(const uint4*)&XRS[(size_t)i * 128 + sub * 8], xr0, xr1, xr2, xr3);
    float4 atA = *(const float4*)&att[sub * 8];
    float4 atB = *(const float4*)&att[sub * 8 + 4];
    f2 at0 = {atA.x, atA.y}, at1 = {atA.z, atA.w};
    f2 at2 = {atB.x, atB.y}, at3 = {atB.z, atB.w};

    f2 ag0 = {0.f, 0.f}, ag1 = {0.f, 0.f}, ag2 = {0.f, 0.f}, ag3 = {0.f, 0.f};
    float denom = 0.f;
    int beg = offsets[i], end = offsets[i + 1];

    for (int j0 = beg; j0 < end; j0 += 8) {
        int jE = j0 + grp;
        bool v = jE < end;
        int sE = csr[v ? jE : beg];
        f2 x0, x1, x2, x3;
        unpack8(*(const uint4*)&Xlb[(size_t)sE * 64 + sub * 8], x0, x1, x2, x3);

        f2 s0 = x0 + xr0, s1 = x1 + xr1, s2 = x2 + xr2, s3 = x3 + xr3;
        f2 l0 = { fmaxf(s0.x, 0.2f * s0.x), fmaxf(s0.y, 0.2f * s0.y) };
        f2 l1 = { fmaxf(s1.x, 0.2f * s1.x), fmaxf(s1.y, 0.2f * s1.y) };
        f2 l2 = { fmaxf(s2.x, 0.2f * s2.x), fmaxf(s2.y, 0.2f * s2.y) };
        f2 l3 = { fmaxf(s3.x, 0.2f * s3.x), fmaxf(s3.y, 0.2f * s3.y) };

        f2 tv = l0 * at0 + l1 * at1;           // pk_mul + pk_fma
        tv += l2 * at2;
        tv += l3 * at3;
        float t = group_sum8(tv.x + tv.y);     // 3 DPP steps: full dot over 64 features
        float a = v ? __expf(t) : 0.f;

        f2 av = {a, a};
        ag0 += av * x0;
        ag1 += av * x1;
        ag2 += av * x2;
        ag3 += av * x3;
        denom += a;
    }

    // combine the 8 edge groups (once per node): 9 values over xor8/xor16/xor32
    float r0 = cross_group(ag0.x), r1 = cross_group(ag0.y);
    float r2 = cross_group(ag1.x), r3 = cross_group(ag1.y);
    float r4 = cross_group(ag2.x), r5 = cross_group(ag2.y);
    float r6 = cross_group(ag3.x), r7 = cross_group(ag3.y);
    denom = cross_group(denom);

    float inv = (denom > 0.f) ? (1.0f / denom) : 0.f;
    f2 sk0, sk1, sk2, sk3;
    unpack8(*(const uint4*)&XRS[(size_t)i * 128 + 64 + sub * 8], sk0, sk1, sk2, sk3);
    float4 bgA = *(const float4*)&bg[sub * 8];
    float4 bgB = *(const float4*)&bg[sub * 8 + 4];
    float e0 = r0 * inv + bgA.x + sk0.x;
    float e1 = r1 * inv + bgA.y + sk0.y;
    float e2 = r2 * inv + bgA.z + sk1.x;
    float e3 = r3 * inv + bgA.w + sk1.y;
    float e4 = r4 * inv + bgB.x + sk2.x;
    float e5 = r5 * inv + bgB.y + sk2.y;
    float e6 = r6 * inv + bgB.z + sk3.x;
    float e7 = r7 * inv + bgB.w + sk3.y;
    if (do_relu) {
        e0 = fmaxf(e0, 0.f); e1 = fmaxf(e1, 0.f); e2 = fmaxf(e2, 0.f); e3 = fmaxf(e3, 0.f);
        e4 = fmaxf(e4, 0.f); e5 = fmaxf(e5, 0.f); e6 = fmaxf(e6, 0.f); e7 = fmaxf(e7, 0.f);
    }
    if (do_out) {
        // Wout rows sub*8+k (k=0..7), cols {0,1}: 16 consecutive floats at Wout[sub*16]
        float4 wA = *(const float4*)&Wout[sub * 16];
        float4 wB = *(const float4*)&Wout[sub * 16 + 4];
        float4 wC = *(const float4*)&Wout[sub * 16 + 8];
        float4 wD = *(const float4*)&Wout[sub * 16 + 12];
        float o0 = e0 * wA.x + e1 * wA.z + e2 * wB.x + e3 * wB.z
                 + e4 * wC.x + e5 * wC.z + e6 * wD.x + e7 * wD.z;
        float o1 = e0 * wA.y + e1 * wA.w + e2 * wB.y + e3 * wB.w
                 + e4 * wC.y + e5 * wC.w + e6 * wD.y + e7 * wD.w;
        o0 = group_sum8(o0);
        o1 = group_sum8(o1);
        if (lane == 0) {
            outp[(size_t)i * 2 + 0] = o0 + bout[0];
            outp[(size_t)i * 2 + 1] = o1 + bout[1];
        }
    } else {
        if (grp == 0) {
            uint4 hh;
            hh.x = (unsigned)bf16_rne(e0) | ((unsigned)bf16_rne(e1) << 16);
            hh.y = (unsigned)bf16_rne(e2) | ((unsigned)bf16_rne(e3) << 16);
            hh.z = (unsigned)bf16_rne(e4) | ((unsigned)bf16_rne(e5) << 16);
            hh.w = (unsigned)bf16_rne(e6) | ((unsigned)bf16_rne(e7) << 16);
            *(uint4*)&hout[(size_t)i * 64 + sub * 8] = hh;
        }
    }
}

// ---------------- launch ----------------

extern "C" void kernel_launch(void* const* d_in, const int* in_sizes, int n_in,
                              void* d_out, int out_size, void* d_ws, size_t ws_size,
                              hipStream_t stream) {
    const float* x    = (const float*)d_in[0];
    const int*   ei   = (const int*)d_in[1];
    const float* Wl   = (const float*)d_in[2];
    const float* bl   = (const float*)d_in[3];
    const float* Wr   = (const float*)d_in[4];
    const float* br   = (const float*)d_in[5];
    const float* att  = (const float*)d_in[6];
    const float* bg   = (const float*)d_in[7];
    const float* Ws   = (const float*)d_in[8];
    const float* bs   = (const float*)d_in[9];
    const float* Wout = (const float*)d_in[10];
    const float* bout = (const float*)d_in[11];
    float* out = (float*)d_out;

    size_t off = 0;
    char* base = (char*)d_ws;
    auto alloc = [&](size_t bytes) -> void* {
        void* p = base + off;
        off += (bytes + 255) & ~(size_t)255;
        return p;
    };
    unsigned short* Xlb = (unsigned short*)alloc((size_t)NN * 64 * 2);
    unsigned short* XRS = (unsigned short*)alloc((size_t)NN * 128 * 2);
    unsigned short* Ahi = (unsigned short*)alloc((size_t)NN * 64 * 2);
    unsigned short* Bhi = (unsigned short*)alloc((size_t)NN * 64 * 2);
    unsigned short* Wthi = (unsigned short*)alloc((size_t)9 * 4096 * 2);
    unsigned short* Wtlo = (unsigned short*)alloc((size_t)9 * 4096 * 2);
    int*  bhistPart = (int*)alloc((size_t)SCWG * NBUCK * 4);
    int*  bbase  = (int*)alloc((size_t)(NBUCK + 1) * 4);
    int*  bcur   = (int*)alloc((size_t)NBUCK * 4);
    unsigned int* bedges = (unsigned int*)alloc((size_t)EE * 4);
    int*  offs   = (int*)alloc((size_t)(NN + 1) * 4);
    int*  csr    = (int*)alloc((size_t)EE * 4);

    const int* src = ei;
    const int* dst = ei + EE;

    hist_conv<<<SCWG + 144 + 400, 256, 0, stream>>>(dst, bhistPart, Wl, Wr, Ws, x,
                                                    Wthi, Wtlo, Ahi);
    bucket_scan<<<1, 512, 0, stream>>>(bhistPart, bbase, bcur, offs);
    bucket_scatter<<<SCWG, 256, 0, stream>>>(src, dst, bhistPart, bcur, bedges);
    bucket_csr<<<NBUCK, 256, 0, stream>>>(bedges, bbase, offs, csr);

    unsigned short* cur = Ahi;
    unsigned short* nxt = Bhi;
    for (int L = 0; L < 3; L++) {
        gemm_mfma<<<(NN + 127) / 128, 256, 0, stream>>>(
            cur, Wthi + (size_t)L * 3 * 4096, Wtlo + (size_t)L * 3 * 4096,
            bl + L * 64, br + L * 64, bs + L * 64, Xlb, XRS);
        node_kernel<<<NN / 4, 256, 0, stream>>>(
            Xlb, XRS, offs, csr, att + L * 64, bg + L * 64,
            nxt, (L < 2) ? 1 : 0,
            Wout, bout, out, (L == 2) ? 1 : 0);
        unsigned short* tp = cur; cur = nxt; nxt = tp;
    }
}

// Round 20
// 331.036 us; speedup vs baseline: 2.2004x; 1.0151x over previous
//
#include <hip/hip_runtime.h>
#include <stdint.h>

#define NN 100000
#define EE 1600000
#define DD 64
#define NBUCK 391        // ceil(NN/256): bucket b covers nodes [b*256, b*256+255]
#define SCWG 200         // hist/scatter workgroups; 8000 edges each
#define SCCHUNK 8000

using short8 = __attribute__((ext_vector_type(8))) short;
using f32x4  = __attribute__((ext_vector_type(4))) float;
using f2     = __attribute__((ext_vector_type(2))) float;

// ---------------- bf16 helpers ----------------

__device__ __forceinline__ unsigned short bf16_rne(float f) {
    unsigned int u = __float_as_uint(f);
    unsigned int r = (u + 0x7FFFu + ((u >> 16) & 1u)) >> 16;
    return (unsigned short)r;
}
__device__ __forceinline__ float bf16_to_f32(unsigned short h) {
    return __uint_as_float(((unsigned int)h) << 16);
}
__device__ __forceinline__ void unpack4(uint2 u, f2& v01, f2& v23) {
    v01 = f2{ __uint_as_float(u.x << 16), __uint_as_float(u.x & 0xFFFF0000u) };
    v23 = f2{ __uint_as_float(u.y << 16), __uint_as_float(u.y & 0xFFFF0000u) };
}

// ---------------- fused histogram (per-block partials, no atomics) + conversions ----------------
// blocks [0,SCWG): edge histogram -> bhistPart[b][NBUCK]
// blocks [SCWG, SCWG+144): weight transpose+split
// blocks [SCWG+144, ...): x -> bf16

__global__ void hist_conv(const int* __restrict__ dst, int* __restrict__ bhistPart,
                          const float* __restrict__ Wl, const float* __restrict__ Wr,
                          const float* __restrict__ Ws, const float* __restrict__ x,
                          unsigned short* __restrict__ Wt_hi, unsigned short* __restrict__ Wt_lo,
                          unsigned short* __restrict__ Ahi) {
    int b = blockIdx.x;
    int t = threadIdx.x;
    if (b < SCWG) {
        __shared__ int h[NBUCK];
        for (int i = t; i < NBUCK; i += 256) h[i] = 0;
        __syncthreads();
        int start = b * SCCHUNK;
        int endi = min(start + SCCHUNK, EE);
        for (int e = start + t; e < endi; e += 256)
            atomicAdd(&h[dst[e] >> 8], 1);
        __syncthreads();
        for (int i = t; i < NBUCK; i += 256)
            bhistPart[b * NBUCK + i] = h[i];               // coalesced, non-atomic
    } else if (b < SCWG + 144) {
        int e = (b - SCWG) * 256 + t;
        if (e >= 9 * 4096) return;
        int mat = e >> 12;          // 0..8 = L*3 + j
        int r   = e & 4095;
        int k   = r >> 6, n = r & 63;
        int L = mat / 3, j = mat % 3;
        const float* W = (j == 0) ? Wl : ((j == 1) ? Wr : Ws);
        float v = W[L * 4096 + k * 64 + n];
        unsigned short hi = bf16_rne(v);
        unsigned short lo = bf16_rne(v - bf16_to_f32(hi));
        Wt_hi[mat * 4096 + n * 64 + k] = hi;
        Wt_lo[mat * 4096 + n * 64 + k] = lo;
    } else {
        int i = (b - SCWG - 144) * 256 + t;                // one float4 per thread
        int total = NN * 16;
        int stride = (gridDim.x - SCWG - 144) * 256;
        for (; i < total; i += stride) {
            float4 v = *(const float4*)&x[(size_t)i * 4];
            ushort4 h;
            h.x = bf16_rne(v.x);
            h.y = bf16_rne(v.y);
            h.z = bf16_rne(v.z);
            h.w = bf16_rne(v.w);
            *(ushort4*)&Ahi[(size_t)i * 4] = h;
        }
    }
}

// scan over summed partials -> bbase/bcursor
__global__ void bucket_scan(const int* __restrict__ bhistPart, int* __restrict__ bbase,
                            int* __restrict__ bcursor, int* __restrict__ offsets) {
    __shared__ int s[512];
    int t = threadIdx.x;
    int v = 0;
    if (t < NBUCK) {
        for (int w = 0; w < SCWG; w++) v += bhistPart[w * NBUCK + t];
    }
    s[t] = v;
    __syncthreads();
    for (int off = 1; off < 512; off <<= 1) {
        int a = (t >= off) ? s[t - off] : 0;
        __syncthreads();
        s[t] += a;
        __syncthreads();
    }
    if (t < NBUCK) { int excl = s[t] - v; bbase[t] = excl; bcursor[t] = excl; }
    if (t == 0) { bbase[NBUCK] = EE; offsets[NN] = EE; }
}

// scatter reuses this block's partial histogram (one pass over edges)
__global__ void bucket_scatter(const int* __restrict__ src, const int* __restrict__ dst,
                               const int* __restrict__ bhistPart,
                               int* __restrict__ bcursor, unsigned int* __restrict__ bedges) {
    __shared__ int lcur[NBUCK];
    int t = threadIdx.x;
    int b = blockIdx.x;
    for (int i = t; i < NBUCK; i += 256) {
        int c = bhistPart[b * NBUCK + i];
        lcur[i] = c ? atomicAdd(&bcursor[i], c) : 0;       // reserve contiguous run
    }
    __syncthreads();
    int start = b * SCCHUNK;
    int endi = min(start + SCCHUNK, EE);
    for (int e = start + t; e < endi; e += 256) {
        int d = dst[e];
        int pos = atomicAdd(&lcur[d >> 8], 1);
        bedges[pos] = ((unsigned int)(d & 255) << 24) | (unsigned int)src[e];
    }
}

__global__ void bucket_csr(const unsigned int* __restrict__ bedges, const int* __restrict__ bbase,
                           int* __restrict__ offsets, int* __restrict__ csr) {
    __shared__ int ncnt[256];
    __shared__ int lofs[256];
    int b = blockIdx.x;
    int t = threadIdx.x;
    int beg = bbase[b], endb = bbase[b + 1];
    ncnt[t] = 0;
    __syncthreads();
    for (int e = beg + t; e < endb; e += 256)
        atomicAdd(&ncnt[bedges[e] >> 24], 1);
    __syncthreads();
    int v = ncnt[t];
    lofs[t] = v;
    __syncthreads();
    for (int off = 1; off < 256; off <<= 1) {
        int a = (t >= off) ? lofs[t - off] : 0;
        __syncthreads();
        lofs[t] += a;
        __syncthreads();
    }
    int excl = lofs[t] - v;
    int node = b * 256 + t;
    if (node < NN) offsets[node] = beg + excl;
    __syncthreads();
    ncnt[t] = beg + excl;                  // reuse as cursor
    __syncthreads();
    for (int e = beg + t; e < endb; e += 256) {
        unsigned int ed = bedges[e];
        int pos = atomicAdd(&ncnt[ed >> 24], 1);
        csr[pos] = (int)(ed & 0xFFFFFFu);
    }
}

// ---------------- MFMA GEMM: A bf16 x split-bf16 W, 32 rows/wave (unchanged) ----------------

__global__ __launch_bounds__(256) void gemm_mfma(
    const unsigned short* __restrict__ Ahi,
    const unsigned short* __restrict__ Wt_hi, const unsigned short* __restrict__ Wt_lo,
    const float* __restrict__ bl, const float* __restrict__ br, const float* __restrict__ bs,
    unsigned short* __restrict__ Xlb, unsigned short* __restrict__ XRS) {
    int lane = threadIdx.x & 63;
    int wid  = threadIdx.x >> 6;
    int m0 = (blockIdx.x * 4 + wid) * 32;
    if (m0 >= NN) return;

    int l4 = lane & 15;
    int hi = lane >> 4;
    int koff = hi * 8;

    int arow0 = m0 + l4, arow1 = m0 + 16 + l4;
    bool ok0 = arow0 < NN, ok1 = arow1 < NN;
    int ar0 = ok0 ? arow0 : NN - 1;
    int ar1 = ok1 ? arow1 : NN - 1;

    const unsigned short* ab0 = Ahi + (size_t)ar0 * 64;
    const unsigned short* ab1 = Ahi + (size_t)ar1 * 64;
    short8 a0k0 = *(const short8*)(ab0 + koff);
    short8 a0k1 = *(const short8*)(ab0 + 32 + koff);
    short8 a1k0 = *(const short8*)(ab1 + koff);
    short8 a1k1 = *(const short8*)(ab1 + 32 + koff);

    int nbase0 = hi * 4;

#pragma unroll
    for (int m = 0; m < 3; m++) {
        const unsigned short* wh = Wt_hi + m * 4096;
        const unsigned short* wl = Wt_lo + m * 4096;
        const float* bias = (m == 0) ? bl : ((m == 1) ? br : bs);
#pragma unroll
        for (int tt = 0; tt < 4; tt++) {
            int ncol = tt * 16 + l4;                  // weight load row
            const unsigned short* bh = wh + ncol * 64 + koff;
            const unsigned short* blo = wl + ncol * 64 + koff;
            short8 bhi0 = *(const short8*)bh;
            short8 bhi1 = *(const short8*)(bh + 32);
            short8 blo0 = *(const short8*)blo;
            short8 blo1 = *(const short8*)(blo + 32);

            f32x4 acc0 = {0.f, 0.f, 0.f, 0.f};
            f32x4 acc1 = {0.f, 0.f, 0.f, 0.f};
            acc0 = __builtin_amdgcn_mfma_f32_16x16x32_bf16(bhi0, a0k0, acc0, 0, 0, 0);
            acc1 = __builtin_amdgcn_mfma_f32_16x16x32_bf16(bhi0, a1k0, acc1, 0, 0, 0);
            acc0 = __builtin_amdgcn_mfma_f32_16x16x32_bf16(bhi1, a0k1, acc0, 0, 0, 0);
            acc1 = __builtin_amdgcn_mfma_f32_16x16x32_bf16(bhi1, a1k1, acc1, 0, 0, 0);
            acc0 = __builtin_amdgcn_mfma_f32_16x16x32_bf16(blo0, a0k0, acc0, 0, 0, 0);
            acc1 = __builtin_amdgcn_mfma_f32_16x16x32_bf16(blo0, a1k0, acc1, 0, 0, 0);
            acc0 = __builtin_amdgcn_mfma_f32_16x16x32_bf16(blo1, a0k1, acc0, 0, 0, 0);
            acc1 = __builtin_amdgcn_mfma_f32_16x16x32_bf16(blo1, a1k1, acc1, 0, 0, 0);

            int nb = tt * 16 + nbase0;                // first of 4 consecutive output cols
            float4 bb = *(const float4*)&bias[nb];
            ushort4 h0, h1;
            h0.x = bf16_rne(acc0[0] + bb.x); h0.y = bf16_rne(acc0[1] + bb.y);
            h0.z = bf16_rne(acc0[2] + bb.z); h0.w = bf16_rne(acc0[3] + bb.w);
            h1.x = bf16_rne(acc1[0] + bb.x); h1.y = bf16_rne(acc1[1] + bb.y);
            h1.z = bf16_rne(acc1[2] + bb.z); h1.w = bf16_rne(acc1[3] + bb.w);
            if (m == 0) {
                if (ok0) *(ushort4*)&Xlb[(size_t)ar0 * 64 + nb] = h0;
                if (ok1) *(ushort4*)&Xlb[(size_t)ar1 * 64 + nb] = h1;
            } else {
                int coff = (m == 1) ? 0 : 64;
                if (ok0) *(ushort4*)&XRS[(size_t)ar0 * 128 + coff + nb] = h0;
                if (ok1) *(ushort4*)&XRS[(size_t)ar1 * 128 + coff + nb] = h1;
            }
        }
    }
}

// ---------------- per-node attention aggregation (R12/R18 structure: 16 lanes/edge, 8 edges/iter, 2 chains) ----------------

__device__ __forceinline__ float group_sum16(float t) {
    t += __int_as_float(__builtin_amdgcn_update_dpp(0, __float_as_int(t), 0xB1, 0xF, 0xF, true));   // xor1
    t += __int_as_float(__builtin_amdgcn_update_dpp(0, __float_as_int(t), 0x4E, 0xF, 0xF, true));   // xor2
    t += __int_as_float(__builtin_amdgcn_update_dpp(0, __float_as_int(t), 0x141, 0xF, 0xF, true));  // row_half_mirror ~ xor4
    t += __int_as_float(__builtin_amdgcn_update_dpp(0, __float_as_int(t), 0x140, 0xF, 0xF, true));  // row_mirror ~ xor8
    return t;
}

__global__ __launch_bounds__(256) void node_kernel(
    const unsigned short* __restrict__ Xlb, const unsigned short* __restrict__ XRS,
    const int* __restrict__ offsets, const int* __restrict__ csr,
    const float* __restrict__ att, const float* __restrict__ bg,
    unsigned short* __restrict__ hout, int do_relu,
    const float* __restrict__ Wout, const float* __restrict__ bout,
    float* __restrict__ outp, int do_out) {
    int lane = threadIdx.x & 63;
    int wid  = threadIdx.x >> 6;
    int i = blockIdx.x * 4 + wid;
    if (i >= NN) return;
    int sub = lane & 15;
    int grp = lane >> 4;

    f2 xr01, xr23;
    unpack4(*(const uint2*)&XRS[(size_t)i * 128 + sub * 4], xr01, xr23);
    float4 att4 = *(const float4*)&att[sub * 4];
    f2 at01 = {att4.x, att4.y}, at23 = {att4.z, att4.w};

    f2 agg01 = {0.f, 0.f}, agg23 = {0.f, 0.f};
    float denom = 0.f;
    int beg = offsets[i], end = offsets[i + 1];

    for (int j0 = beg; j0 < end; j0 += 8) {
        int jA = j0 + grp, jB = jA + 4;
        bool vA = jA < end, vB = jB < end;
        int sA = csr[vA ? jA : beg];
        int sB = csr[vB ? jB : beg];
        uint2 uA = *(const uint2*)&Xlb[(size_t)sA * 64 + sub * 4];
        uint2 uB = *(const uint2*)&Xlb[(size_t)sB * 64 + sub * 4];
        f2 xA01, xA23, xB01, xB23;
        unpack4(uA, xA01, xA23);
        unpack4(uB, xB01, xB23);

        f2 sA01 = xA01 + xr01;                 // v_pk_add_f32
        f2 sA23 = xA23 + xr23;
        f2 sB01 = xB01 + xr01;
        f2 sB23 = xB23 + xr23;
        f2 lA01 = { fmaxf(sA01.x, 0.2f * sA01.x), fmaxf(sA01.y, 0.2f * sA01.y) };
        f2 lA23 = { fmaxf(sA23.x, 0.2f * sA23.x), fmaxf(sA23.y, 0.2f * sA23.y) };
        f2 lB01 = { fmaxf(sB01.x, 0.2f * sB01.x), fmaxf(sB01.y, 0.2f * sB01.y) };
        f2 lB23 = { fmaxf(sB23.x, 0.2f * sB23.x), fmaxf(sB23.y, 0.2f * sB23.y) };

        f2 tAv = lA01 * at01 + lA23 * at23;    // pk_mul + pk_fma
        f2 tBv = lB01 * at01 + lB23 * at23;
        float tA = group_sum16(tAv.x + tAv.y);
        float tB = group_sum16(tBv.x + tBv.y);
        float aA = vA ? __expf(tA) : 0.f;
        float aB = vB ? __expf(tB) : 0.f;

        f2 aAv = {aA, aA};
        f2 aBv = {aB, aB};
        agg01 += aAv * xA01 + aBv * xB01;      // pk_fma chain
        agg23 += aAv * xA23 + aBv * xB23;
        denom += aA + aB;
    }

    float aggx = agg01.x, aggy = agg01.y, aggz = agg23.x, aggw = agg23.y;
#pragma unroll
    for (int m = 16; m <= 32; m <<= 1) {
        aggx  += __shfl_xor(aggx, m, 64);
        aggy  += __shfl_xor(aggy, m, 64);
        aggz  += __shfl_xor(aggz, m, 64);
        aggw  += __shfl_xor(aggw, m, 64);
        denom += __shfl_xor(denom, m, 64);
    }

    float inv = (denom > 0.f) ? (1.0f / denom) : 0.f;
    f2 sk01, sk23;
    unpack4(*(const uint2*)&XRS[(size_t)i * 128 + 64 + sub * 4], sk01, sk23);
    float4 bg4 = *(const float4*)&bg[sub * 4];
    float4 res;
    res.x = aggx * inv + bg4.x + sk01.x;
    res.y = aggy * inv + bg4.y + sk01.y;
    res.z = aggz * inv + bg4.z + sk23.x;
    res.w = aggw * inv + bg4.w + sk23.y;
    if (do_relu) {
        res.x = fmaxf(res.x, 0.f); res.y = fmaxf(res.y, 0.f);
        res.z = fmaxf(res.z, 0.f); res.w = fmaxf(res.w, 0.f);
    }
    if (do_out) {
        float4 w01 = *(const float4*)&Wout[8 * sub];
        float4 w23 = *(const float4*)&Wout[8 * sub + 4];
        float o0 = res.x * w01.x + res.y * w01.z + res.z * w23.x + res.w * w23.z;
        float o1 = res.x * w01.y + res.y * w01.w + res.z * w23.y + res.w * w23.w;
        o0 = group_sum16(o0);
        o1 = group_sum16(o1);
        if (lane == 0) {
            outp[(size_t)i * 2 + 0] = o0 + bout[0];
            outp[(size_t)i * 2 + 1] = o1 + bout[1];
        }
    } else {
        if (grp == 0) {
            ushort4 h;
            h.x = bf16_rne(res.x);
            h.y = bf16_rne(res.y);
            h.z = bf16_rne(res.z);
            h.w = bf16_rne(res.w);
            *(ushort4*)&hout[(size_t)i * 64 + sub * 4] = h;
        }
    }
}

// ---------------- launch ----------------

extern "C" void kernel_launch(void* const* d_in, const int* in_sizes, int n_in,
                              void* d_out, int out_size, void* d_ws, size_t ws_size,
                              hipStream_t stream) {
    const float* x    = (const float*)d_in[0];
    const int*   ei   = (const int*)d_in[1];
    const float* Wl   = (const float*)d_in[2];
    const float* bl   = (const float*)d_in[3];
    const float* Wr   = (const float*)d_in[4];
    const float* br   = (const float*)d_in[5];
    const float* att  = (const float*)d_in[6];
    const float* bg   = (const float*)d_in[7];
    const float* Ws   = (const float*)d_in[8];
    const float* bs   = (const float*)d_in[9];
    const float* Wout = (const float*)d_in[10];
    const float* bout = (const float*)d_in[11];
    float* out = (float*)d_out;

    size_t off = 0;
    char* base = (char*)d_ws;
    auto alloc = [&](size_t bytes) -> void* {
        void* p = base + off;
        off += (bytes + 255) & ~(size_t)255;
        return p;
    };
    unsigned short* Xlb = (unsigned short*)alloc((size_t)NN * 64 * 2);
    unsigned short* XRS = (unsigned short*)alloc((size_t)NN * 128 * 2);
    unsigned short* Ahi = (unsigned short*)alloc((size_t)NN * 64 * 2);
    unsigned short* Bhi = (unsigned short*)alloc((size_t)NN * 64 * 2);
    unsigned short* Wthi = (unsigned short*)alloc((size_t)9 * 4096 * 2);
    unsigned short* Wtlo = (unsigned short*)alloc((size_t)9 * 4096 * 2);
    int*  bhistPart = (int*)alloc((size_t)SCWG * NBUCK * 4);
    int*  bbase  = (int*)alloc((size_t)(NBUCK + 1) * 4);
    int*  bcur   = (int*)alloc((size_t)NBUCK * 4);
    unsigned int* bedges = (unsigned int*)alloc((size_t)EE * 4);
    int*  offs   = (int*)alloc((size_t)(NN + 1) * 4);
    int*  csr    = (int*)alloc((size_t)EE * 4);

    const int* src = ei;
    const int* dst = ei + EE;

    hist_conv<<<SCWG + 144 + 400, 256, 0, stream>>>(dst, bhistPart, Wl, Wr, Ws, x,
                                                    Wthi, Wtlo, Ahi);
    bucket_scan<<<1, 512, 0, stream>>>(bhistPart, bbase, bcur, offs);
    bucket_scatter<<<SCWG, 256, 0, stream>>>(src, dst, bhistPart, bcur, bedges);
    bucket_csr<<<NBUCK, 256, 0, stream>>>(bedges, bbase, offs, csr);

    unsigned short* cur = Ahi;
    unsigned short* nxt = Bhi;
    for (int L = 0; L < 3; L++) {
        gemm_mfma<<<(NN + 127) / 128, 256, 0, stream>>>(
            cur, Wthi + (size_t)L * 3 * 4096, Wtlo + (size_t)L * 3 * 4096,
            bl + L * 64, br + L * 64, bs + L * 64, Xlb, XRS);
        node_kernel<<<NN / 4, 256, 0, stream>>>(
            Xlb, XRS, offs, csr, att + L * 64, bg + L * 64,
            nxt, (L < 2) ? 1 : 0,
            Wout, bout, out, (L == 2) ? 1 : 0);
        unsigned short* tp = cur; cur = nxt; nxt = tp;
    }
}